// Round 10
// baseline (184.414 us; speedup 1.0000x reference)
//
#include <hip/hip_runtime.h>

// PositionalWordEmbedding: out[b,s,d] = W[x[b,s]][d] + pe[s][d]
// B=32, S=4096, D=256, VOCAB=50257. Output fp32, 128 MiB -> memory-bound.
//
// R7: 79 us @ 22-33% HBM, Occ 33% -> latency-bound (1024 blocks, 32 serial
//     gathers/thread).
// R9: BPT 32->4, grid 8192, nontemporal stores: pwe ~58 us (out of top-5;
//     harness dur 205->184). Still above the ~32 us roofline
//     (201 MB @ 6.3 TB/s; fillBuffer hits 6.6 TB/s on this chip).
// R10: BPT 4->2, grid 16384 (4M threads): 2x independent gather chains
//     machine-wide to hide the token->row dependent-load latency. Trig
//     recompute (2 powf + 2 sincos per thread) ~6.6 us machine-wide VALU,
//     hidden under memory.

#define SEQ   4096
#define DIM   256
#define BATCH 32
#define D4    (DIM / 4)      // 64 float4 per row
#define BPT   2              // batches per thread
#define NGRP  (BATCH / BPT)  // 16 batch-groups
#define SD    (SEQ * D4)     // 262144 = 2^18 (s,d4) slots

typedef float f32x4 __attribute__((ext_vector_type(4)));

__global__ __launch_bounds__(256)
void pwe_kernel(const int* __restrict__ x,
                const f32x4* __restrict__ W4,
                f32x4* __restrict__ out4) {
    int tid = blockIdx.x * blockDim.x + threadIdx.x;   // 0 .. SD*NGRP-1
    int sd  = tid & (SD - 1);     // (s,d4), wave-aligned: lanes share s
    int bg  = tid >> 18;          // batch group 0..15
    int s   = sd >> 6;            // sequence position (uniform per wave)
    int d4  = sd & 63;            // float4 index within row
    int d0  = d4 * 4;             // dims d0(e), d0+1(o), d0+2(e), d0+3(o)

    // pe for this thread's 4 dims (precise math: args up to ~4095 rad)
    float f0 = powf(10000.0f, -(float)d0       / (float)DIM);
    float f2 = powf(10000.0f, -(float)(d0 + 2) / (float)DIM);
    float p  = (float)s;
    float s0, c0, s2, c2;
    sincosf(p * f0, &s0, &c0);
    sincosf(p * f2, &s2, &c2);
    f32x4 pe;
    pe.x = s0; pe.y = c0; pe.z = s2; pe.w = c2;

    const int b0 = bg * BPT;

    // issue all token loads first (independent, wave-uniform broadcasts)
    int tok[BPT];
    #pragma unroll
    for (int i = 0; i < BPT; ++i)
        tok[i] = x[(b0 + i) * SEQ + s];

    #pragma unroll
    for (int i = 0; i < BPT; ++i) {
        f32x4 w = W4[(size_t)tok[i] * D4 + d4];           // coalesced row gather
        f32x4 o = w + pe;
        __builtin_nontemporal_store(
            o, &out4[((size_t)(b0 + i) * SEQ + s) * D4 + d4]);  // coalesced
    }
}

extern "C" void kernel_launch(void* const* d_in, const int* in_sizes, int n_in,
                              void* d_out, int out_size, void* d_ws, size_t ws_size,
                              hipStream_t stream) {
    const int*   x = (const int*)d_in[0];      // [32, 4096] token ids
    const float* W = (const float*)d_in[1];    // [50257, 256] fp32
    float*     out = (float*)d_out;            // [32, 4096, 256] fp32

    const int total = SD * NGRP;               // 4,194,304 threads
    const int block = 256;
    const int grid  = total / block;           // 16384 blocks
    pwe_kernel<<<grid, block, 0, stream>>>(x, (const f32x4*)W, (f32x4*)out);
}